// Round 8
// baseline (739.394 us; speedup 1.0000x reference)
//
#include <hip/hip_runtime.h>
#include <cstdint>
#include <cstddef>

#define FEAT 128
#define PSLICE 8
#define BSHIFT 7          // 128 nodes per bucket
#define CAP 4096          // bucket capacity (mean 2048 for E=1.6M, N=100k)

typedef _Float16 h16;
typedef __attribute__((ext_vector_type(8))) _Float16 h16x8;
typedef __attribute__((ext_vector_type(4))) _Float16 h16x4;
typedef __attribute__((ext_vector_type(4))) float f32x4;

// ---------- fp32 -> fp16 bulk convert (8 elems/thread) ----------
__global__ __launch_bounds__(256) void k_cvt(const float* __restrict__ X,
    h16* __restrict__ Y, int nv) {   // nv = total elements / 8
  int i = blockIdx.x * 256 + threadIdx.x;
  if (i < nv) {
    const float* p = X + (size_t)i * 8;
    float4 a = *(const float4*)p, b = *(const float4*)(p + 4);
    h16x8 o;
    o[0] = (h16)a.x; o[1] = (h16)a.y; o[2] = (h16)a.z; o[3] = (h16)a.w;
    o[4] = (h16)b.x; o[5] = (h16)b.y; o[6] = (h16)b.z; o[7] = (h16)b.w;
    *(h16x8*)&Y[(size_t)i * 8] = o;
  }
}

// ---------- pass 1: block-level radix partition; packed (src<<7 | dstLocal) ----------
__global__ __launch_bounds__(256) void k_part(const int* __restrict__ ei,
    unsigned int* __restrict__ pair, int* __restrict__ gcur, int E, int nb) {
  __shared__ int cnt[1024];
  __shared__ int base[1024];
  int per = (E + gridDim.x - 1) / gridDim.x;
  int e0 = blockIdx.x * per;
  int e1 = min(e0 + per, E);
  for (int i = threadIdx.x; i < nb; i += 256) cnt[i] = 0;
  __syncthreads();
  for (int e = e0 + threadIdx.x; e < e1; e += 256)
    atomicAdd(&cnt[ei[E + e] >> BSHIFT], 1);
  __syncthreads();
  for (int i = threadIdx.x; i < nb; i += 256) {
    int c = cnt[i];
    base[i] = c ? atomicAdd(&gcur[i], c) : 0;
    cnt[i] = 0;   // reuse as intra-block cursor
  }
  __syncthreads();
  for (int e = e0 + threadIdx.x; e < e1; e += 256) {
    int src = ei[e];
    int dst = ei[E + e];
    int b = dst >> BSHIFT;
    int pos = base[b] + atomicAdd(&cnt[b], 1);
    if (pos < CAP) pair[(size_t)b * CAP + pos] = ((unsigned)src << BSHIFT) | (unsigned)(dst & 127);
  }
}

// ---------- small scan over bucket counts -> bucket offsets ----------
__global__ __launch_bounds__(1024) void k_bscan(const int* __restrict__ cnt,
    int* __restrict__ boffs, int* __restrict__ offs, int nb, int N, int E) {
  __shared__ int wsum[16];
  __shared__ int carry;
  int tid = threadIdx.x;
  int lane = tid & 63;
  int wid = tid >> 6;
  if (tid == 0) carry = 0;
  for (int base = 0; base < nb; base += 1024) {
    __syncthreads();
    int c0 = carry;
    int i = base + tid;
    int v = (i < nb) ? cnt[i] : 0;
    int x = v;
#pragma unroll
    for (int off = 1; off < 64; off <<= 1) {
      int t = __shfl_up(x, off);
      if (lane >= off) x += t;
    }
    if (lane == 63) wsum[wid] = x;
    __syncthreads();
    if (wid == 0) {
      int t = (lane < 16) ? wsum[lane] : 0;
#pragma unroll
      for (int off = 1; off < 16; off <<= 1) {
        int u = __shfl_up(t, off);
        if (lane >= off) t += u;
      }
      if (lane < 16) wsum[lane] = t;
    }
    __syncthreads();
    int wex = (wid == 0) ? 0 : wsum[wid - 1];
    int o = c0 + wex + (x - v);   // exclusive prefix
    if (i < nb) boffs[i] = o;
    int total = wsum[15];
    __syncthreads();
    if (tid == 0) carry = c0 + total;
  }
  __syncthreads();
  if (tid == 0) { boffs[nb] = carry; offs[N] = E; }
}

// ---------- pass 2: per-bucket count/scan/scatter -> csr, offs, dinv ----------
__global__ __launch_bounds__(256) void k_bucket(const unsigned int* __restrict__ pair,
    const int* __restrict__ bcnt, const int* __restrict__ boffs,
    int* __restrict__ csr, int* __restrict__ offs, float* __restrict__ dinv,
    int N) {
  int b = blockIdx.x;
  int m = min(bcnt[b], CAP);
  __shared__ int cnt[128];
  __shared__ int noff[128];
  __shared__ int w0tot;
  if (threadIdx.x < 128) cnt[threadIdx.x] = 0;
  __syncthreads();
  const unsigned int* p = pair + (size_t)b * CAP;
  for (int i = threadIdx.x; i < m; i += 256)
    atomicAdd(&cnt[p[i] & 127u], 1);
  __syncthreads();
  int v = 0, x = 0;
  int lane = threadIdx.x & 63, w = threadIdx.x >> 6;
  if (threadIdx.x < 128) {
    v = cnt[threadIdx.x];
    x = v;
#pragma unroll
    for (int o = 1; o < 64; o <<= 1) {
      int t = __shfl_up(x, o);
      if (lane >= o) x += t;
    }
    if (threadIdx.x == 63) w0tot = x;
  }
  __syncthreads();
  int cbase = boffs[b];
  if (threadIdx.x < 128) {
    int ex = x - v + ((w == 1) ? w0tot : 0);
    int g = (b << BSHIFT) + threadIdx.x;
    if (g < N) {
      offs[g] = cbase + ex;
      dinv[g] = 1.0f / sqrtf((float)v + 1.0f);
    }
    noff[threadIdx.x] = ex;
    cnt[threadIdx.x] = 0;
  }
  __syncthreads();
  for (int i = threadIdx.x; i < m; i += 256) {
    unsigned pk = p[i];
    int d = pk & 127u;
    int pos = cbase + noff[d] + atomicAdd(&cnt[d], 1);
    csr[pos] = (int)(pk >> BSHIFT);
  }
}

// ---------- W prep: fp32 [k][col] -> fp16 transposed [col][k] ----------
__global__ __launch_bounds__(256) void k_wprep(const float* __restrict__ W,
    h16* __restrict__ WT) {
  int i = blockIdx.x * 256 + threadIdx.x;
  int k = i >> 7, c = i & 127;
  WT[c * FEAT + k] = (h16)W[(size_t)k * FEAT + c];
}

// ---------- shared gather core: fp32 sum of self + CSR neighbors (4 feats) ----------
__device__ inline float4 ldrow4(const h16* p) {
  h16x4 v = *(const h16x4*)p;
  return make_float4((float)v[0], (float)v[1], (float)v[2], (float)v[3]);
}

__device__ inline float4 gather_row(const h16* __restrict__ XW,
    const int* __restrict__ offs, const int* __restrict__ csr, int node, int f) {
  float4 a0 = ldrow4(&XW[(size_t)node * FEAT + f]);  // self term
  float4 a1 = {0,0,0,0}, a2 = {0,0,0,0}, a3 = {0,0,0,0};
  float4 a4 = {0,0,0,0}, a5 = {0,0,0,0}, a6 = {0,0,0,0}, a7 = {0,0,0,0};
  int s = offs[node], e = offs[node + 1];
  int i = s;
  for (; i + 8 <= e; i += 8) {
    int s0 = csr[i + 0], s1 = csr[i + 1], s2 = csr[i + 2], s3 = csr[i + 3];
    int s4 = csr[i + 4], s5 = csr[i + 5], s6 = csr[i + 6], s7 = csr[i + 7];
    float4 v0 = ldrow4(&XW[(size_t)s0 * FEAT + f]);
    float4 v1 = ldrow4(&XW[(size_t)s1 * FEAT + f]);
    float4 v2 = ldrow4(&XW[(size_t)s2 * FEAT + f]);
    float4 v3 = ldrow4(&XW[(size_t)s3 * FEAT + f]);
    float4 v4 = ldrow4(&XW[(size_t)s4 * FEAT + f]);
    float4 v5 = ldrow4(&XW[(size_t)s5 * FEAT + f]);
    float4 v6 = ldrow4(&XW[(size_t)s6 * FEAT + f]);
    float4 v7 = ldrow4(&XW[(size_t)s7 * FEAT + f]);
    a0.x += v0.x; a0.y += v0.y; a0.z += v0.z; a0.w += v0.w;
    a1.x += v1.x; a1.y += v1.y; a1.z += v1.z; a1.w += v1.w;
    a2.x += v2.x; a2.y += v2.y; a2.z += v2.z; a2.w += v2.w;
    a3.x += v3.x; a3.y += v3.y; a3.z += v3.z; a3.w += v3.w;
    a4.x += v4.x; a4.y += v4.y; a4.z += v4.z; a4.w += v4.w;
    a5.x += v5.x; a5.y += v5.y; a5.z += v5.z; a5.w += v5.w;
    a6.x += v6.x; a6.y += v6.y; a6.z += v6.z; a6.w += v6.w;
    a7.x += v7.x; a7.y += v7.y; a7.z += v7.z; a7.w += v7.w;
  }
  if (i + 4 <= e) {
    int s0 = csr[i + 0], s1 = csr[i + 1], s2 = csr[i + 2], s3 = csr[i + 3];
    float4 v0 = ldrow4(&XW[(size_t)s0 * FEAT + f]);
    float4 v1 = ldrow4(&XW[(size_t)s1 * FEAT + f]);
    float4 v2 = ldrow4(&XW[(size_t)s2 * FEAT + f]);
    float4 v3 = ldrow4(&XW[(size_t)s3 * FEAT + f]);
    a4.x += v0.x; a4.y += v0.y; a4.z += v0.z; a4.w += v0.w;
    a5.x += v1.x; a5.y += v1.y; a5.z += v1.z; a5.w += v1.w;
    a6.x += v2.x; a6.y += v2.y; a6.z += v2.z; a6.w += v2.w;
    a7.x += v3.x; a7.y += v3.y; a7.z += v3.z; a7.w += v3.w;
    i += 4;
  }
  for (; i < e; ++i) {
    int s0 = csr[i];
    float4 v0 = ldrow4(&XW[(size_t)s0 * FEAT + f]);
    a1.x += v0.x; a1.y += v0.y; a1.z += v0.z; a1.w += v0.w;
  }
  a0.x += a1.x; a0.y += a1.y; a0.z += a1.z; a0.w += a1.w;
  a2.x += a3.x; a2.y += a3.y; a2.z += a3.z; a2.w += a3.w;
  a4.x += a5.x; a4.y += a5.y; a4.z += a5.z; a4.w += a5.w;
  a6.x += a7.x; a6.y += a7.y; a6.z += a7.z; a6.w += a7.w;
  a0.x += a2.x; a0.y += a2.y; a0.z += a2.z; a0.w += a2.w;
  a4.x += a6.x; a4.y += a6.y; a4.z += a6.z; a4.w += a6.w;
  a0.x += a4.x; a0.y += a4.y; a0.z += a4.z; a0.w += a4.w;
  return a0;
}

// -------- standalone aggregation (feeds pool) --------
__global__ __launch_bounds__(256) void k_agg(const h16* __restrict__ XW,
    const int* __restrict__ offs, const int* __restrict__ csr,
    const float* __restrict__ dinv, const float* __restrict__ bias,
    h16* __restrict__ out, int n) {
  int half = threadIdx.x >> 5;
  int lane = threadIdx.x & 31;
  int node = blockIdx.x * 8 + half;
  if (node >= n) return;
  int f = lane * 4;
  float4 a = gather_row(XW, offs, csr, node, f);
  float d = dinv[node];
  float4 b = *(const float4*)&bias[f];
  h16x4 o;
  o[0] = (h16)fmaxf(a.x * d + b.x, 0.f);
  o[1] = (h16)fmaxf(a.y * d + b.y, 0.f);
  o[2] = (h16)fmaxf(a.z * d + b.z, 0.f);
  o[3] = (h16)fmaxf(a.w * d + b.w, 0.f);
  *(h16x4*)&out[(size_t)node * FEAT + f] = o;
}

// -------- fused aggregation + pvec: p = sigmoid(relu(conv2) @ fcw + fcb) --------
__global__ __launch_bounds__(256) void k_agg_pvec(const h16* __restrict__ XW,
    const int* __restrict__ offs, const int* __restrict__ csr,
    const float* __restrict__ dinv, const float* __restrict__ bias,
    const float* __restrict__ fcw, const float* __restrict__ fcb,
    float* __restrict__ p, int n) {
  int half = threadIdx.x >> 5;
  int lane = threadIdx.x & 31;
  int node = blockIdx.x * 8 + half;
  if (node >= n) return;
  int f = lane * 4;
  float4 a = gather_row(XW, offs, csr, node, f);
  float d = dinv[node];
  float4 b = *(const float4*)&bias[f];
  float4 wv = *(const float4*)&fcw[f];
  float acc = fmaxf(a.x * d + b.x, 0.f) * wv.x
            + fmaxf(a.y * d + b.y, 0.f) * wv.y
            + fmaxf(a.z * d + b.z, 0.f) * wv.z
            + fmaxf(a.w * d + b.w, 0.f) * wv.w;
#pragma unroll
  for (int off = 16; off > 0; off >>= 1) acc += __shfl_xor(acc, off, 32);
  if (lane == 0) p[node] = 1.0f / (1.0f + expf(-(acc + fcb[0])));
}

// -------- fused aggregation (conv1 finish) + MFMA GEMM (conv2 start) --------
// 512 threads, 128 nodes/block. Y[i] = (relu(dinv*agg+b) @ W) * dinv
__global__ __launch_bounds__(512) void k_agg_gemm(const h16* __restrict__ XW,
    const int* __restrict__ offs, const int* __restrict__ csr,
    const float* __restrict__ dinv, const float* __restrict__ bias,
    const h16* __restrict__ WT, h16* __restrict__ Y, int n) {
  __shared__ __align__(16) h16 lA[128 * FEAT];   // 32 KB, swizzled [row][k]
  __shared__ __align__(16) h16 lB[128 * FEAT];   // 32 KB, swizzled [col][k]
  int tid = threadIdx.x;
  int row0 = blockIdx.x * 128;
  // stage WT (independent of gather)
#pragma unroll
  for (int i = 0; i < 4; ++i) {
    int c = tid + i * 512;          // 2048 16B-chunks
    int col = c >> 4, kc = c & 15;
    h16x8 v = *(const h16x8*)&WT[col * FEAT + kc * 8];
    int byte = col * 256 + ((kc * 16) ^ ((col & 7) << 4));
    *(h16x8*)((char*)lB + byte) = v;
  }
  // gather phase: half-wave per node, 8 nodes each
  int half = tid >> 5;   // 0..15
  int lane = tid & 31;
  int f = lane * 4;
  float4 bv = *(const float4*)&bias[f];
  for (int q = 0; q < 8; ++q) {
    int r = half * 8 + q;
    int node = row0 + r;
    h16x4 o;
    if (node < n) {
      float4 a = gather_row(XW, offs, csr, node, f);
      float d = dinv[node];
      o[0] = (h16)fmaxf(a.x * d + bv.x, 0.f);
      o[1] = (h16)fmaxf(a.y * d + bv.y, 0.f);
      o[2] = (h16)fmaxf(a.z * d + bv.z, 0.f);
      o[3] = (h16)fmaxf(a.w * d + bv.w, 0.f);
    } else {
      o[0] = (h16)0.f; o[1] = (h16)0.f; o[2] = (h16)0.f; o[3] = (h16)0.f;
    }
    int byte = r * 256 + ((f * 2) ^ ((r & 7) << 4));
    *(h16x4*)((char*)lA + byte) = o;
  }
  __syncthreads();
  // MFMA phase: 8 waves; wave w owns rows [w*16, w*16+16)
  int w = tid >> 6, l = tid & 63;
  int lr = l & 15, lq = l >> 4;
  h16x8 af[4];
#pragma unroll
  for (int s = 0; s < 4; ++s) {
    int r = w * 16 + lr;
    int k2 = (s * 32 + lq * 8) * 2;
    int byte = r * 256 + (k2 ^ ((r & 7) << 4));
    af[s] = *(const h16x8*)((const char*)lA + byte);
  }
  f32x4 acc[8];
#pragma unroll
  for (int nn = 0; nn < 8; ++nn) acc[nn] = (f32x4){0.f, 0.f, 0.f, 0.f};
#pragma unroll
  for (int nn = 0; nn < 8; ++nn) {
#pragma unroll
    for (int s = 0; s < 4; ++s) {
      int col = nn * 16 + lr;
      int k2 = (s * 32 + lq * 8) * 2;
      int byte = col * 256 + (k2 ^ ((col & 7) << 4));
      h16x8 bf = *(const h16x8*)((const char*)lB + byte);
      acc[nn] = __builtin_amdgcn_mfma_f32_16x16x32_f16(af[s], bf, acc[nn], 0, 0, 0);
    }
  }
#pragma unroll
  for (int r = 0; r < 4; ++r) {
    int grow = row0 + w * 16 + lq * 4 + r;
    if (grow < n) {
      float sc = dinv[grow];
#pragma unroll
      for (int nn = 0; nn < 8; ++nn)
        Y[(size_t)grow * FEAT + nn * 16 + lr] = (h16)(acc[nn][r] * sc);
    }
  }
}

// ---------------- standalone MFMA GEMM (first layer of each chain) ----------------
__device__ inline h16x8 load8(const float* p) {
  float4 a = *(const float4*)p, b = *(const float4*)(p + 4);
  h16x8 o;
  o[0] = (h16)a.x; o[1] = (h16)a.y; o[2] = (h16)a.z; o[3] = (h16)a.w;
  o[4] = (h16)b.x; o[5] = (h16)b.y; o[6] = (h16)b.z; o[7] = (h16)b.w;
  return o;
}
__device__ inline h16x8 load8(const h16* p) { return *(const h16x8*)p; }

template <typename TI>
__global__ __launch_bounds__(256) void k_gemm_mfma(const TI* __restrict__ X,
    const h16* __restrict__ WT, const float* __restrict__ s1, const float* __restrict__ s2,
    h16* __restrict__ Y, int n) {
  __shared__ __align__(16) h16 lA[128 * FEAT];
  __shared__ __align__(16) h16 lB[128 * FEAT];
  int tid = threadIdx.x;
  int row0 = blockIdx.x * 128;
#pragma unroll
  for (int i = 0; i < 8; ++i) {
    int c = tid + i * 256;
    int r = c >> 4, kc = c & 15;
    int grow = row0 + r;
    h16x8 v;
#pragma unroll
    for (int j = 0; j < 8; ++j) v[j] = (h16)0.f;
    if (grow < n) v = load8(&X[(size_t)grow * FEAT + kc * 8]);
    int byte = r * 256 + ((kc * 16) ^ ((r & 7) << 4));
    *(h16x8*)((char*)lA + byte) = v;
  }
#pragma unroll
  for (int i = 0; i < 8; ++i) {
    int c = tid + i * 256;
    int col = c >> 4, kc = c & 15;
    h16x8 v = *(const h16x8*)&WT[col * FEAT + kc * 8];
    int byte = col * 256 + ((kc * 16) ^ ((col & 7) << 4));
    *(h16x8*)((char*)lB + byte) = v;
  }
  __syncthreads();
  int w = tid >> 6, l = tid & 63;
  int lr = l & 15, lq = l >> 4;
  h16x8 af[2][4];
#pragma unroll
  for (int m = 0; m < 2; ++m)
#pragma unroll
    for (int s = 0; s < 4; ++s) {
      int r = w * 32 + m * 16 + lr;
      int k2 = (s * 32 + lq * 8) * 2;
      int byte = r * 256 + (k2 ^ ((r & 7) << 4));
      af[m][s] = *(const h16x8*)((const char*)lA + byte);
    }
  f32x4 acc[2][8];
#pragma unroll
  for (int m = 0; m < 2; ++m)
#pragma unroll
    for (int nn = 0; nn < 8; ++nn) acc[m][nn] = (f32x4){0.f, 0.f, 0.f, 0.f};
#pragma unroll
  for (int nn = 0; nn < 8; ++nn) {
#pragma unroll
    for (int s = 0; s < 4; ++s) {
      int col = nn * 16 + lr;
      int k2 = (s * 32 + lq * 8) * 2;
      int byte = col * 256 + (k2 ^ ((col & 7) << 4));
      h16x8 bf = *(const h16x8*)((const char*)lB + byte);
      acc[0][nn] = __builtin_amdgcn_mfma_f32_16x16x32_f16(af[0][s], bf, acc[0][nn], 0, 0, 0);
      acc[1][nn] = __builtin_amdgcn_mfma_f32_16x16x32_f16(af[1][s], bf, acc[1][nn], 0, 0, 0);
    }
  }
#pragma unroll
  for (int m = 0; m < 2; ++m) {
#pragma unroll
    for (int r = 0; r < 4; ++r) {
      int grow = row0 + w * 32 + m * 16 + lq * 4 + r;
      if (grow < n) {
        float sc = 1.0f;
        if (s1) sc = s1[grow];
        if (s2) sc *= s2[grow];
#pragma unroll
        for (int nn = 0; nn < 8; ++nn)
          Y[(size_t)grow * FEAT + nn * 16 + lr] = (h16)(acc[m][nn][r] * sc);
      }
    }
  }
}

// ---------- mean pool, stage 1: per-(graph,slice) partial sums ----------
__global__ __launch_bounds__(256) void k_pool_part(const h16* __restrict__ Z,
    const int* __restrict__ batch, float* __restrict__ part, int n) {
  int g = blockIdx.x / PSLICE;
  int s = blockIdx.x % PSLICE;
  int lo = 0, hi = n;
  while (lo < hi) { int m = (lo + hi) >> 1; if (batch[m] < g) lo = m + 1; else hi = m; }
  int start = lo;
  hi = n;
  while (lo < hi) { int m = (lo + hi) >> 1; if (batch[m] <= g) lo = m + 1; else hi = m; }
  int end = lo;
  int len = end - start;
  int per = (len + PSLICE - 1) / PSLICE;
  int r0 = start + s * per;
  int r1 = min(r0 + per, end);
  int f = threadIdx.x & 127;
  int half = threadIdx.x >> 7;
  float acc = 0.f;
  for (int i = r0 + half; i < r1; i += 2) acc += (float)Z[(size_t)i * FEAT + f];
  __shared__ float lds[256];
  lds[threadIdx.x] = acc;
  __syncthreads();
  if (half == 0) part[(size_t)blockIdx.x * FEAT + f] = lds[f] + lds[128 + f];
}

// ---------- mean pool, stage 2 ----------
__global__ __launch_bounds__(128) void k_pool_fin(const float* __restrict__ part,
    const int* __restrict__ batch, float* __restrict__ out, int n) {
  int g = blockIdx.x;
  int lo = 0, hi = n;
  while (lo < hi) { int m = (lo + hi) >> 1; if (batch[m] < g) lo = m + 1; else hi = m; }
  int start = lo;
  hi = n;
  while (lo < hi) { int m = (lo + hi) >> 1; if (batch[m] <= g) lo = m + 1; else hi = m; }
  int len = lo - start;
  int f = threadIdx.x;
  float tot = 0.f;
#pragma unroll
  for (int s = 0; s < PSLICE; ++s) tot += part[(size_t)(g * PSLICE + s) * FEAT + f];
  out[(size_t)g * FEAT + f] = tot / fmaxf((float)len, 1.0f);
}

extern "C" void kernel_launch(void* const* d_in, const int* in_sizes, int n_in,
                              void* d_out, int out_size, void* d_ws, size_t ws_size,
                              hipStream_t stream) {
  const float* x_H    = (const float*)d_in[0];
  const int*   ei_H   = (const int*)d_in[1];
  const float* x_G    = (const float*)d_in[2];
  const int*   ei_G   = (const int*)d_in[3];
  const int*   bat_H  = (const int*)d_in[4];
  const int*   bat_G  = (const int*)d_in[5];
  const float* sel_W1 = (const float*)d_in[6];
  const float* sel_b1 = (const float*)d_in[7];
  const float* sel_W2 = (const float*)d_in[8];
  const float* sel_b2 = (const float*)d_in[9];
  const float* sel_fcw = (const float*)d_in[10];
  const float* sel_fcb = (const float*)d_in[11];
  const float* emb_W1 = (const float*)d_in[12];
  const float* emb_b1 = (const float*)d_in[13];
  const float* emb_W2 = (const float*)d_in[14];
  const float* emb_b2 = (const float*)d_in[15];

  const int N = in_sizes[0] / FEAT;
  const int E = in_sizes[1] / 2;
  const int NG = 64;
  const int NB = (N + 127) >> BSHIFT;

  float* out = (float*)d_out;
  float* hF = out;
  float* hG = out + NG * FEAT;
  float* p  = out + 2 * NG * FEAT;

  char* ws = (char*)d_ws;
  size_t off = 0;
  auto alloc = [&](size_t bytes) -> void* {
    void* ptr = (void*)(ws + off);
    off += (bytes + 511) & ~(size_t)511;
    return ptr;
  };
  const size_t SZH = (size_t)N * FEAT * sizeof(h16);          // 25.6 MB
  const size_t SZP = (size_t)NB * CAP * sizeof(unsigned int); // 12.8 MB
  const size_t SZB = SZH > SZP ? SZH : SZP;
  h16* A       = (h16*)alloc(SZB);
  h16* B       = (h16*)alloc(SZB);
  h16* C       = (h16*)alloc(SZH);
  h16* x16H    = (h16*)alloc(SZH);
  float* dinvH = (float*)alloc((size_t)N * 4);
  float* dinvG = (float*)alloc((size_t)N * 4);
  int*  offsH  = (int*)alloc((size_t)(N + 1) * 4);
  int*  offsG  = (int*)alloc((size_t)(N + 1) * 4);
  int*  csrH   = (int*)alloc((size_t)E * 4);
  int*  csrG   = (int*)alloc((size_t)E * 4);
  int*  gcurH  = (int*)alloc((size_t)NB * 4);
  int*  gcurG  = (int*)alloc((size_t)NB * 4);
  int*  boffsH = (int*)alloc((size_t)(NB + 1) * 4);
  int*  boffsG = (int*)alloc((size_t)(NB + 1) * 4);
  float* part  = (float*)alloc((size_t)NG * PSLICE * FEAT * 4);
  h16* wtSel1  = (h16*)alloc((size_t)FEAT * FEAT * 2);
  h16* wtSel2  = (h16*)alloc((size_t)FEAT * FEAT * 2);
  h16* wtEmb1  = (h16*)alloc((size_t)FEAT * FEAT * 2);
  h16* wtEmb2  = (h16*)alloc((size_t)FEAT * FEAT * 2);
  (void)ws_size;

  unsigned int* pairH = (unsigned int*)A;
  unsigned int* pairG = (unsigned int*)B;

  const int gGemm = (N + 127) / 128;
  const int gAgg  = (N + 7) / 8;
  const int gAG   = (N + 127) / 128;

  // ---- weight prep + x_H fp16 convert ----
  k_wprep<<<64, 256, 0, stream>>>(sel_W1, wtSel1);
  k_wprep<<<64, 256, 0, stream>>>(sel_W2, wtSel2);
  k_wprep<<<64, 256, 0, stream>>>(emb_W1, wtEmb1);
  k_wprep<<<64, 256, 0, stream>>>(emb_W2, wtEmb2);
  k_cvt<<<(N * FEAT / 8 + 255) / 256, 256, 0, stream>>>(x_H, x16H, N * FEAT / 8);

  // ---- build CSR for H and G via radix partition ----
  hipMemsetAsync(gcurH, 0, (size_t)NB * 4, stream);
  hipMemsetAsync(gcurG, 0, (size_t)NB * 4, stream);
  k_part<<<256, 256, 0, stream>>>(ei_H, pairH, gcurH, E, NB);
  k_part<<<256, 256, 0, stream>>>(ei_G, pairG, gcurG, E, NB);
  k_bscan<<<1, 1024, 0, stream>>>(gcurH, boffsH, offsH, NB, N, E);
  k_bscan<<<1, 1024, 0, stream>>>(gcurG, boffsG, offsG, NB, N, E);
  k_bucket<<<NB, 256, 0, stream>>>(pairH, gcurH, boffsH, csrH, offsH, dinvH, N);
  k_bucket<<<NB, 256, 0, stream>>>(pairG, gcurG, boffsG, csrG, offsG, dinvG, N);

  // ---- selector: gemm1 -> fused agg+gemm2 -> fused agg+pvec ----
  k_gemm_mfma<h16><<<gGemm, 256, 0, stream>>>(x16H, wtSel1, dinvH, nullptr, A, N);
  k_agg_gemm<<<gAG, 512, 0, stream>>>(A, offsH, csrH, dinvH, sel_b1, wtSel2, C, N);
  k_agg_pvec<<<gAgg, 256, 0, stream>>>(C, offsH, csrH, dinvH, sel_b2, sel_fcw, sel_fcb, p, N);

  // ---- F branch ----
  k_gemm_mfma<h16><<<gGemm, 256, 0, stream>>>(x16H, wtEmb1, dinvH, p, A, N);
  k_agg_gemm<<<gAG, 512, 0, stream>>>(A, offsH, csrH, dinvH, emb_b1, wtEmb2, C, N);
  k_agg<<<gAgg, 256, 0, stream>>>(C, offsH, csrH, dinvH, emb_b2, B, N);
  k_pool_part<<<NG * PSLICE, 256, 0, stream>>>(B, bat_H, part, N);
  k_pool_fin<<<NG, 128, 0, stream>>>(part, bat_H, hF, N);

  // ---- G branch ----
  k_gemm_mfma<float><<<gGemm, 256, 0, stream>>>(x_G, wtEmb1, dinvG, nullptr, A, N);
  k_agg_gemm<<<gAG, 512, 0, stream>>>(A, offsG, csrG, dinvG, emb_b1, wtEmb2, C, N);
  k_agg<<<gAgg, 256, 0, stream>>>(C, offsG, csrG, dinvG, emb_b2, B, N);
  k_pool_part<<<NG * PSLICE, 256, 0, stream>>>(B, bat_G, part, N);
  k_pool_fin<<<NG, 128, 0, stream>>>(part, bat_G, hG, N);
}

// Round 10
// 709.473 us; speedup vs baseline: 1.0422x; 1.0422x over previous
//
#include <hip/hip_runtime.h>
#include <cstdint>
#include <cstddef>

#define FEAT 128
#define PSLICE 8
#define BSHIFT 7          // 128 nodes per bucket
#define CAP 4096          // bucket capacity (mean 2048 for E=1.6M, N=100k)

typedef _Float16 h16;
typedef __attribute__((ext_vector_type(8))) _Float16 h16x8;
typedef __attribute__((ext_vector_type(4))) _Float16 h16x4;
typedef __attribute__((ext_vector_type(4))) float f32x4;

// ---------- fp32 -> fp16 bulk convert (8 elems/thread) ----------
__global__ __launch_bounds__(256) void k_cvt(const float* __restrict__ X,
    h16* __restrict__ Y, int nv) {
  int i = blockIdx.x * 256 + threadIdx.x;
  if (i < nv) {
    const float* p = X + (size_t)i * 8;
    float4 a = *(const float4*)p, b = *(const float4*)(p + 4);
    h16x8 o;
    o[0] = (h16)a.x; o[1] = (h16)a.y; o[2] = (h16)a.z; o[3] = (h16)a.w;
    o[4] = (h16)b.x; o[5] = (h16)b.y; o[6] = (h16)b.z; o[7] = (h16)b.w;
    *(h16x8*)&Y[(size_t)i * 8] = o;
  }
}

// ---------- pass 1: block-level radix partition; packed (src<<7 | dstLocal) ----------
__global__ __launch_bounds__(256) void k_part(const int* __restrict__ ei,
    unsigned int* __restrict__ pair, int* __restrict__ gcur, int E, int nb) {
  __shared__ int cnt[1024];
  __shared__ int base[1024];
  int per = (E + gridDim.x - 1) / gridDim.x;
  int e0 = blockIdx.x * per;
  int e1 = min(e0 + per, E);
  for (int i = threadIdx.x; i < nb; i += 256) cnt[i] = 0;
  __syncthreads();
  for (int e = e0 + threadIdx.x; e < e1; e += 256)
    atomicAdd(&cnt[ei[E + e] >> BSHIFT], 1);
  __syncthreads();
  for (int i = threadIdx.x; i < nb; i += 256) {
    int c = cnt[i];
    base[i] = c ? atomicAdd(&gcur[i], c) : 0;
    cnt[i] = 0;   // reuse as intra-block cursor
  }
  __syncthreads();
  for (int e = e0 + threadIdx.x; e < e1; e += 256) {
    int src = ei[e];
    int dst = ei[E + e];
    int b = dst >> BSHIFT;
    int pos = base[b] + atomicAdd(&cnt[b], 1);
    if (pos < CAP) pair[(size_t)b * CAP + pos] = ((unsigned)src << BSHIFT) | (unsigned)(dst & 127);
  }
}

// ---------- small scan over bucket counts -> bucket offsets ----------
__global__ __launch_bounds__(1024) void k_bscan(const int* __restrict__ cnt,
    int* __restrict__ boffs, int* __restrict__ offs, int nb, int N, int E) {
  __shared__ int wsum[16];
  __shared__ int carry;
  int tid = threadIdx.x;
  int lane = tid & 63;
  int wid = tid >> 6;
  if (tid == 0) carry = 0;
  for (int base = 0; base < nb; base += 1024) {
    __syncthreads();
    int c0 = carry;
    int i = base + tid;
    int v = (i < nb) ? cnt[i] : 0;
    int x = v;
#pragma unroll
    for (int off = 1; off < 64; off <<= 1) {
      int t = __shfl_up(x, off);
      if (lane >= off) x += t;
    }
    if (lane == 63) wsum[wid] = x;
    __syncthreads();
    if (wid == 0) {
      int t = (lane < 16) ? wsum[lane] : 0;
#pragma unroll
      for (int off = 1; off < 16; off <<= 1) {
        int u = __shfl_up(t, off);
        if (lane >= off) t += u;
      }
      if (lane < 16) wsum[lane] = t;
    }
    __syncthreads();
    int wex = (wid == 0) ? 0 : wsum[wid - 1];
    int o = c0 + wex + (x - v);
    if (i < nb) boffs[i] = o;
    int total = wsum[15];
    __syncthreads();
    if (tid == 0) carry = c0 + total;
  }
  __syncthreads();
  if (tid == 0) { boffs[nb] = carry; offs[N] = E; }
}

// ---------- pass 2: per-bucket count/scan/scatter -> csr, offs, dinv ----------
__global__ __launch_bounds__(256) void k_bucket(const unsigned int* __restrict__ pair,
    const int* __restrict__ bcnt, const int* __restrict__ boffs,
    int* __restrict__ csr, int* __restrict__ offs, float* __restrict__ dinv,
    int N) {
  int b = blockIdx.x;
  int m = min(bcnt[b], CAP);
  __shared__ int cnt[128];
  __shared__ int noff[128];
  __shared__ int w0tot;
  if (threadIdx.x < 128) cnt[threadIdx.x] = 0;
  __syncthreads();
  const unsigned int* p = pair + (size_t)b * CAP;
  for (int i = threadIdx.x; i < m; i += 256)
    atomicAdd(&cnt[p[i] & 127u], 1);
  __syncthreads();
  int v = 0, x = 0;
  int lane = threadIdx.x & 63, w = threadIdx.x >> 6;
  if (threadIdx.x < 128) {
    v = cnt[threadIdx.x];
    x = v;
#pragma unroll
    for (int o = 1; o < 64; o <<= 1) {
      int t = __shfl_up(x, o);
      if (lane >= o) x += t;
    }
    if (threadIdx.x == 63) w0tot = x;
  }
  __syncthreads();
  int cbase = boffs[b];
  if (threadIdx.x < 128) {
    int ex = x - v + ((w == 1) ? w0tot : 0);
    int g = (b << BSHIFT) + threadIdx.x;
    if (g < N) {
      offs[g] = cbase + ex;
      dinv[g] = 1.0f / sqrtf((float)v + 1.0f);
    }
    noff[threadIdx.x] = ex;
    cnt[threadIdx.x] = 0;
  }
  __syncthreads();
  for (int i = threadIdx.x; i < m; i += 256) {
    unsigned pk = p[i];
    int d = pk & 127u;
    int pos = cbase + noff[d] + atomicAdd(&cnt[d], 1);
    csr[pos] = (int)(pk >> BSHIFT);
  }
}

// ---------- W prep: fp32 [k][col] -> fp16 transposed [col][k] ----------
__global__ __launch_bounds__(256) void k_wprep(const float* __restrict__ W,
    h16* __restrict__ WT) {
  int i = blockIdx.x * 256 + threadIdx.x;
  int k = i >> 7, c = i & 127;
  WT[c * FEAT + k] = (h16)W[(size_t)k * FEAT + c];
}

// ---------- shared gather core ----------
__device__ inline float4 ldrow4(const h16* p) {
  h16x4 v = *(const h16x4*)p;
  return make_float4((float)v[0], (float)v[1], (float)v[2], (float)v[3]);
}

__device__ inline float4 gather_row(const h16* __restrict__ XW,
    const int* __restrict__ offs, const int* __restrict__ csr, int node, int f) {
  float4 a0 = ldrow4(&XW[(size_t)node * FEAT + f]);  // self term
  float4 a1 = {0,0,0,0}, a2 = {0,0,0,0}, a3 = {0,0,0,0};
  float4 a4 = {0,0,0,0}, a5 = {0,0,0,0}, a6 = {0,0,0,0}, a7 = {0,0,0,0};
  int s = offs[node], e = offs[node + 1];
  int i = s;
  for (; i + 8 <= e; i += 8) {
    int s0 = csr[i + 0], s1 = csr[i + 1], s2 = csr[i + 2], s3 = csr[i + 3];
    int s4 = csr[i + 4], s5 = csr[i + 5], s6 = csr[i + 6], s7 = csr[i + 7];
    float4 v0 = ldrow4(&XW[(size_t)s0 * FEAT + f]);
    float4 v1 = ldrow4(&XW[(size_t)s1 * FEAT + f]);
    float4 v2 = ldrow4(&XW[(size_t)s2 * FEAT + f]);
    float4 v3 = ldrow4(&XW[(size_t)s3 * FEAT + f]);
    float4 v4 = ldrow4(&XW[(size_t)s4 * FEAT + f]);
    float4 v5 = ldrow4(&XW[(size_t)s5 * FEAT + f]);
    float4 v6 = ldrow4(&XW[(size_t)s6 * FEAT + f]);
    float4 v7 = ldrow4(&XW[(size_t)s7 * FEAT + f]);
    a0.x += v0.x; a0.y += v0.y; a0.z += v0.z; a0.w += v0.w;
    a1.x += v1.x; a1.y += v1.y; a1.z += v1.z; a1.w += v1.w;
    a2.x += v2.x; a2.y += v2.y; a2.z += v2.z; a2.w += v2.w;
    a3.x += v3.x; a3.y += v3.y; a3.z += v3.z; a3.w += v3.w;
    a4.x += v4.x; a4.y += v4.y; a4.z += v4.z; a4.w += v4.w;
    a5.x += v5.x; a5.y += v5.y; a5.z += v5.z; a5.w += v5.w;
    a6.x += v6.x; a6.y += v6.y; a6.z += v6.z; a6.w += v6.w;
    a7.x += v7.x; a7.y += v7.y; a7.z += v7.z; a7.w += v7.w;
  }
  if (i + 4 <= e) {
    int s0 = csr[i + 0], s1 = csr[i + 1], s2 = csr[i + 2], s3 = csr[i + 3];
    float4 v0 = ldrow4(&XW[(size_t)s0 * FEAT + f]);
    float4 v1 = ldrow4(&XW[(size_t)s1 * FEAT + f]);
    float4 v2 = ldrow4(&XW[(size_t)s2 * FEAT + f]);
    float4 v3 = ldrow4(&XW[(size_t)s3 * FEAT + f]);
    a4.x += v0.x; a4.y += v0.y; a4.z += v0.z; a4.w += v0.w;
    a5.x += v1.x; a5.y += v1.y; a5.z += v1.z; a5.w += v1.w;
    a6.x += v2.x; a6.y += v2.y; a6.z += v2.z; a6.w += v2.w;
    a7.x += v3.x; a7.y += v3.y; a7.z += v3.z; a7.w += v3.w;
    i += 4;
  }
  for (; i < e; ++i) {
    int s0 = csr[i];
    float4 v0 = ldrow4(&XW[(size_t)s0 * FEAT + f]);
    a1.x += v0.x; a1.y += v0.y; a1.z += v0.z; a1.w += v0.w;
  }
  a0.x += a1.x; a0.y += a1.y; a0.z += a1.z; a0.w += a1.w;
  a2.x += a3.x; a2.y += a3.y; a2.z += a3.z; a2.w += a3.w;
  a4.x += a5.x; a4.y += a5.y; a4.z += a5.z; a4.w += a5.w;
  a6.x += a7.x; a6.y += a7.y; a6.z += a7.z; a6.w += a7.w;
  a0.x += a2.x; a0.y += a2.y; a0.z += a2.z; a0.w += a2.w;
  a4.x += a6.x; a4.y += a6.y; a4.z += a6.z; a4.w += a6.w;
  a0.x += a4.x; a0.y += a4.y; a0.z += a4.z; a0.w += a4.w;
  return a0;
}

// -------- standalone aggregation --------
__global__ __launch_bounds__(256) void k_agg(const h16* __restrict__ XW,
    const int* __restrict__ offs, const int* __restrict__ csr,
    const float* __restrict__ dinv, const float* __restrict__ bias,
    h16* __restrict__ out, int n) {
  int half = threadIdx.x >> 5;
  int lane = threadIdx.x & 31;
  int node = blockIdx.x * 8 + half;
  if (node >= n) return;
  int f = lane * 4;
  float4 a = gather_row(XW, offs, csr, node, f);
  float d = dinv[node];
  float4 b = *(const float4*)&bias[f];
  h16x4 o;
  o[0] = (h16)fmaxf(a.x * d + b.x, 0.f);
  o[1] = (h16)fmaxf(a.y * d + b.y, 0.f);
  o[2] = (h16)fmaxf(a.z * d + b.z, 0.f);
  o[3] = (h16)fmaxf(a.w * d + b.w, 0.f);
  *(h16x4*)&out[(size_t)node * FEAT + f] = o;
}

// -------- fused aggregation + pvec --------
__global__ __launch_bounds__(256) void k_agg_pvec(const h16* __restrict__ XW,
    const int* __restrict__ offs, const int* __restrict__ csr,
    const float* __restrict__ dinv, const float* __restrict__ bias,
    const float* __restrict__ fcw, const float* __restrict__ fcb,
    float* __restrict__ p, int n) {
  int half = threadIdx.x >> 5;
  int lane = threadIdx.x & 31;
  int node = blockIdx.x * 8 + half;
  if (node >= n) return;
  int f = lane * 4;
  float4 a = gather_row(XW, offs, csr, node, f);
  float d = dinv[node];
  float4 b = *(const float4*)&bias[f];
  float4 wv = *(const float4*)&fcw[f];
  float acc = fmaxf(a.x * d + b.x, 0.f) * wv.x
            + fmaxf(a.y * d + b.y, 0.f) * wv.y
            + fmaxf(a.z * d + b.z, 0.f) * wv.z
            + fmaxf(a.w * d + b.w, 0.f) * wv.w;
#pragma unroll
  for (int off = 16; off > 0; off >>= 1) acc += __shfl_xor(acc, off, 32);
  if (lane == 0) p[node] = 1.0f / (1.0f + expf(-(acc + fcb[0])));
}

// ---------------- MFMA GEMM ----------------
__device__ inline h16x8 load8(const float* p) {
  float4 a = *(const float4*)p, b = *(const float4*)(p + 4);
  h16x8 o;
  o[0] = (h16)a.x; o[1] = (h16)a.y; o[2] = (h16)a.z; o[3] = (h16)a.w;
  o[4] = (h16)b.x; o[5] = (h16)b.y; o[6] = (h16)b.z; o[7] = (h16)b.w;
  return o;
}
__device__ inline h16x8 load8(const h16* p) { return *(const h16x8*)p; }

template <typename TI>
__global__ __launch_bounds__(256) void k_gemm_mfma(const TI* __restrict__ X,
    const h16* __restrict__ WT, const float* __restrict__ s1, const float* __restrict__ s2,
    h16* __restrict__ Y, int n) {
  __shared__ __align__(16) h16 lA[128 * FEAT];
  __shared__ __align__(16) h16 lB[128 * FEAT];
  int tid = threadIdx.x;
  int row0 = blockIdx.x * 128;
#pragma unroll
  for (int i = 0; i < 8; ++i) {
    int c = tid + i * 256;
    int r = c >> 4, kc = c & 15;
    int grow = row0 + r;
    h16x8 v;
#pragma unroll
    for (int j = 0; j < 8; ++j) v[j] = (h16)0.f;
    if (grow < n) v = load8(&X[(size_t)grow * FEAT + kc * 8]);
    int byte = r * 256 + ((kc * 16) ^ ((r & 7) << 4));
    *(h16x8*)((char*)lA + byte) = v;
  }
#pragma unroll
  for (int i = 0; i < 8; ++i) {
    int c = tid + i * 256;
    int col = c >> 4, kc = c & 15;
    h16x8 v = *(const h16x8*)&WT[col * FEAT + kc * 8];
    int byte = col * 256 + ((kc * 16) ^ ((col & 7) << 4));
    *(h16x8*)((char*)lB + byte) = v;
  }
  __syncthreads();
  int w = tid >> 6, l = tid & 63;
  int lr = l & 15, lq = l >> 4;
  h16x8 af[2][4];
#pragma unroll
  for (int m = 0; m < 2; ++m)
#pragma unroll
    for (int s = 0; s < 4; ++s) {
      int r = w * 32 + m * 16 + lr;
      int k2 = (s * 32 + lq * 8) * 2;
      int byte = r * 256 + (k2 ^ ((r & 7) << 4));
      af[m][s] = *(const h16x8*)((const char*)lA + byte);
    }
  f32x4 acc[2][8];
#pragma unroll
  for (int m = 0; m < 2; ++m)
#pragma unroll
    for (int nn = 0; nn < 8; ++nn) acc[m][nn] = (f32x4){0.f, 0.f, 0.f, 0.f};
#pragma unroll
  for (int nn = 0; nn < 8; ++nn) {
#pragma unroll
    for (int s = 0; s < 4; ++s) {
      int col = nn * 16 + lr;
      int k2 = (s * 32 + lq * 8) * 2;
      int byte = col * 256 + (k2 ^ ((col & 7) << 4));
      h16x8 bf = *(const h16x8*)((const char*)lB + byte);
      acc[0][nn] = __builtin_amdgcn_mfma_f32_16x16x32_f16(af[0][s], bf, acc[0][nn], 0, 0, 0);
      acc[1][nn] = __builtin_amdgcn_mfma_f32_16x16x32_f16(af[1][s], bf, acc[1][nn], 0, 0, 0);
    }
  }
#pragma unroll
  for (int m = 0; m < 2; ++m) {
#pragma unroll
    for (int r = 0; r < 4; ++r) {
      int grow = row0 + w * 32 + m * 16 + lq * 4 + r;
      if (grow < n) {
        float sc = 1.0f;
        if (s1) sc = s1[grow];
        if (s2) sc *= s2[grow];
#pragma unroll
        for (int nn = 0; nn < 8; ++nn)
          Y[(size_t)grow * FEAT + nn * 16 + lr] = (h16)(acc[m][nn][r] * sc);
      }
    }
  }
}

// ---------- mean pool, stage 1 ----------
__global__ __launch_bounds__(256) void k_pool_part(const h16* __restrict__ Z,
    const int* __restrict__ batch, float* __restrict__ part, int n) {
  int g = blockIdx.x / PSLICE;
  int s = blockIdx.x % PSLICE;
  int lo = 0, hi = n;
  while (lo < hi) { int m = (lo + hi) >> 1; if (batch[m] < g) lo = m + 1; else hi = m; }
  int start = lo;
  hi = n;
  while (lo < hi) { int m = (lo + hi) >> 1; if (batch[m] <= g) lo = m + 1; else hi = m; }
  int end = lo;
  int len = end - start;
  int per = (len + PSLICE - 1) / PSLICE;
  int r0 = start + s * per;
  int r1 = min(r0 + per, end);
  int f = threadIdx.x & 127;
  int half = threadIdx.x >> 7;
  float acc = 0.f;
  for (int i = r0 + half; i < r1; i += 2) acc += (float)Z[(size_t)i * FEAT + f];
  __shared__ float lds[256];
  lds[threadIdx.x] = acc;
  __syncthreads();
  if (half == 0) part[(size_t)blockIdx.x * FEAT + f] = lds[f] + lds[128 + f];
}

// ---------- mean pool, stage 2 ----------
__global__ __launch_bounds__(128) void k_pool_fin(const float* __restrict__ part,
    const int* __restrict__ batch, float* __restrict__ out, int n) {
  int g = blockIdx.x;
  int lo = 0, hi = n;
  while (lo < hi) { int m = (lo + hi) >> 1; if (batch[m] < g) lo = m + 1; else hi = m; }
  int start = lo;
  hi = n;
  while (lo < hi) { int m = (lo + hi) >> 1; if (batch[m] <= g) lo = m + 1; else hi = m; }
  int len = lo - start;
  int f = threadIdx.x;
  float tot = 0.f;
#pragma unroll
  for (int s = 0; s < PSLICE; ++s) tot += part[(size_t)(g * PSLICE + s) * FEAT + f];
  out[(size_t)g * FEAT + f] = tot / fmaxf((float)len, 1.0f);
}

extern "C" void kernel_launch(void* const* d_in, const int* in_sizes, int n_in,
                              void* d_out, int out_size, void* d_ws, size_t ws_size,
                              hipStream_t stream) {
  const float* x_H    = (const float*)d_in[0];
  const int*   ei_H   = (const int*)d_in[1];
  const float* x_G    = (const float*)d_in[2];
  const int*   ei_G   = (const int*)d_in[3];
  const int*   bat_H  = (const int*)d_in[4];
  const int*   bat_G  = (const int*)d_in[5];
  const float* sel_W1 = (const float*)d_in[6];
  const float* sel_b1 = (const float*)d_in[7];
  const float* sel_W2 = (const float*)d_in[8];
  const float* sel_b2 = (const float*)d_in[9];
  const float* sel_fcw = (const float*)d_in[10];
  const float* sel_fcb = (const float*)d_in[11];
  const float* emb_W1 = (const float*)d_in[12];
  const float* emb_b1 = (const float*)d_in[13];
  const float* emb_W2 = (const float*)d_in[14];
  const float* emb_b2 = (const float*)d_in[15];

  const int N = in_sizes[0] / FEAT;
  const int E = in_sizes[1] / 2;
  const int NG = 64;
  const int NB = (N + 127) >> BSHIFT;

  float* out = (float*)d_out;
  float* hF = out;
  float* hG = out + NG * FEAT;
  float* p  = out + 2 * NG * FEAT;

  char* ws = (char*)d_ws;
  size_t off = 0;
  auto alloc = [&](size_t bytes) -> void* {
    void* ptr = (void*)(ws + off);
    off += (bytes + 511) & ~(size_t)511;
    return ptr;
  };
  const size_t SZH = (size_t)N * FEAT * sizeof(h16);          // 25.6 MB
  const size_t SZP = (size_t)NB * CAP * sizeof(unsigned int); // 12.8 MB
  const size_t SZB = SZH > SZP ? SZH : SZP;
  h16* A       = (h16*)alloc(SZB);
  h16* B       = (h16*)alloc(SZB);
  h16* C       = (h16*)alloc(SZH);
  h16* x16H    = (h16*)alloc(SZH);
  float* dinvH = (float*)alloc((size_t)N * 4);
  float* dinvG = (float*)alloc((size_t)N * 4);
  int*  offsH  = (int*)alloc((size_t)(N + 1) * 4);
  int*  offsG  = (int*)alloc((size_t)(N + 1) * 4);
  int*  csrH   = (int*)alloc((size_t)E * 4);
  int*  csrG   = (int*)alloc((size_t)E * 4);
  int*  gcurH  = (int*)alloc((size_t)NB * 4);
  int*  gcurG  = (int*)alloc((size_t)NB * 4);
  int*  boffsH = (int*)alloc((size_t)(NB + 1) * 4);
  int*  boffsG = (int*)alloc((size_t)(NB + 1) * 4);
  float* part  = (float*)alloc((size_t)NG * PSLICE * FEAT * 4);
  h16* wtSel1  = (h16*)alloc((size_t)FEAT * FEAT * 2);
  h16* wtSel2  = (h16*)alloc((size_t)FEAT * FEAT * 2);
  h16* wtEmb1  = (h16*)alloc((size_t)FEAT * FEAT * 2);
  h16* wtEmb2  = (h16*)alloc((size_t)FEAT * FEAT * 2);
  (void)ws_size;

  unsigned int* pairH = (unsigned int*)A;
  unsigned int* pairG = (unsigned int*)B;

  const int gGemm = (N + 127) / 128;
  const int gAgg  = (N + 7) / 8;

  // ---- weight prep + x_H fp16 convert ----
  k_wprep<<<64, 256, 0, stream>>>(sel_W1, wtSel1);
  k_wprep<<<64, 256, 0, stream>>>(sel_W2, wtSel2);
  k_wprep<<<64, 256, 0, stream>>>(emb_W1, wtEmb1);
  k_wprep<<<64, 256, 0, stream>>>(emb_W2, wtEmb2);
  k_cvt<<<(N * FEAT / 8 + 255) / 256, 256, 0, stream>>>(x_H, x16H, N * FEAT / 8);

  // ---- build CSR for H and G ----
  hipMemsetAsync(gcurH, 0, (size_t)NB * 4, stream);
  hipMemsetAsync(gcurG, 0, (size_t)NB * 4, stream);
  k_part<<<256, 256, 0, stream>>>(ei_H, pairH, gcurH, E, NB);
  k_part<<<256, 256, 0, stream>>>(ei_G, pairG, gcurG, E, NB);
  k_bscan<<<1, 1024, 0, stream>>>(gcurH, boffsH, offsH, NB, N, E);
  k_bscan<<<1, 1024, 0, stream>>>(gcurG, boffsG, offsG, NB, N, E);
  k_bucket<<<NB, 256, 0, stream>>>(pairH, gcurH, boffsH, csrH, offsH, dinvH, N);
  k_bucket<<<NB, 256, 0, stream>>>(pairG, gcurG, boffsG, csrG, offsG, dinvG, N);

  // ---- selector: gemm1 -> agg -> gemm2 -> fused agg+pvec ----
  k_gemm_mfma<h16><<<gGemm, 256, 0, stream>>>(x16H, wtSel1, dinvH, nullptr, A, N);
  k_agg<<<gAgg, 256, 0, stream>>>(A, offsH, csrH, dinvH, sel_b1, B, N);
  k_gemm_mfma<h16><<<gGemm, 256, 0, stream>>>(B, wtSel2, dinvH, nullptr, C, N);
  k_agg_pvec<<<gAgg, 256, 0, stream>>>(C, offsH, csrH, dinvH, sel_b2, sel_fcw, sel_fcb, p, N);

  // ---- F branch ----
  k_gemm_mfma<h16><<<gGemm, 256, 0, stream>>>(x16H, wtEmb1, dinvH, p, A, N);
  k_agg<<<gAgg, 256, 0, stream>>>(A, offsH, csrH, dinvH, emb_b1, B, N);
  k_gemm_mfma<h16><<<gGemm, 256, 0, stream>>>(B, wtEmb2, dinvH, nullptr, C, N);
  k_agg<<<gAgg, 256, 0, stream>>>(C, offsH, csrH, dinvH, emb_b2, B, N);
  k_pool_part<<<NG * PSLICE, 256, 0, stream>>>(B, bat_H, part, N);
  k_pool_fin<<<NG, 128, 0, stream>>>(part, bat_H, hF, N);

  // ---- G branch ----
  k_gemm_mfma<float><<<gGemm, 256, 0, stream>>>(x_G, wtEmb1, dinvG, nullptr, A, N);
  k_agg<<<gAgg, 256, 0, stream>>>(A, offsG, csrG, dinvG, emb_b1, B, N);
  k_gemm_mfma<h16><<<gGemm, 256, 0, stream>>>(B, wtEmb2, dinvG, nullptr, C, N);
  k_agg<<<gAgg, 256, 0, stream>>>(C, offsG, csrG, dinvG, emb_b2, B, N);
  k_pool_part<<<NG * PSLICE, 256, 0, stream>>>(B, bat_G, part, N);
  k_pool_fin<<<NG, 128, 0, stream>>>(part, bat_G, hG, N);
}

// Round 11
// 633.667 us; speedup vs baseline: 1.1668x; 1.1196x over previous
//
#include <hip/hip_runtime.h>
#include <cstdint>
#include <cstddef>

#define FEAT 128
#define PSL2 32           // pool slices for fused agg+pool
#define BSHIFT 7          // 128 nodes per bucket
#define CAP 4096          // bucket capacity (mean 2048 for E=1.6M, N=100k)

typedef _Float16 h16;
typedef __attribute__((ext_vector_type(8))) _Float16 h16x8;
typedef __attribute__((ext_vector_type(4))) float f32x4;

// ---------- fp32 -> fp16 bulk convert (8 elems/thread) ----------
__global__ __launch_bounds__(256) void k_cvt(const float* __restrict__ X,
    h16* __restrict__ Y, int nv) {
  int i = blockIdx.x * 256 + threadIdx.x;
  if (i < nv) {
    const float* p = X + (size_t)i * 8;
    float4 a = *(const float4*)p, b = *(const float4*)(p + 4);
    h16x8 o;
    o[0] = (h16)a.x; o[1] = (h16)a.y; o[2] = (h16)a.z; o[3] = (h16)a.w;
    o[4] = (h16)b.x; o[5] = (h16)b.y; o[6] = (h16)b.z; o[7] = (h16)b.w;
    *(h16x8*)&Y[(size_t)i * 8] = o;
  }
}

// ---------- pass 1: block-level radix partition; packed (src<<7 | dstLocal) ----------
__global__ __launch_bounds__(256) void k_part(const int* __restrict__ ei,
    unsigned int* __restrict__ pair, int* __restrict__ gcur, int E, int nb) {
  __shared__ int cnt[1024];
  __shared__ int base[1024];
  int per = (E + gridDim.x - 1) / gridDim.x;
  int e0 = blockIdx.x * per;
  int e1 = min(e0 + per, E);
  for (int i = threadIdx.x; i < nb; i += 256) cnt[i] = 0;
  __syncthreads();
  for (int e = e0 + threadIdx.x; e < e1; e += 256)
    atomicAdd(&cnt[ei[E + e] >> BSHIFT], 1);
  __syncthreads();
  for (int i = threadIdx.x; i < nb; i += 256) {
    int c = cnt[i];
    base[i] = c ? atomicAdd(&gcur[i], c) : 0;
    cnt[i] = 0;   // reuse as intra-block cursor
  }
  __syncthreads();
  for (int e = e0 + threadIdx.x; e < e1; e += 256) {
    int src = ei[e];
    int dst = ei[E + e];
    int b = dst >> BSHIFT;
    int pos = base[b] + atomicAdd(&cnt[b], 1);
    if (pos < CAP) pair[(size_t)b * CAP + pos] = ((unsigned)src << BSHIFT) | (unsigned)(dst & 127);
  }
}

// ---------- small scan over bucket counts -> bucket offsets ----------
__global__ __launch_bounds__(1024) void k_bscan(const int* __restrict__ cnt,
    int* __restrict__ boffs, int* __restrict__ offs, int nb, int N, int E) {
  __shared__ int wsum[16];
  __shared__ int carry;
  int tid = threadIdx.x;
  int lane = tid & 63;
  int wid = tid >> 6;
  if (tid == 0) carry = 0;
  for (int base = 0; base < nb; base += 1024) {
    __syncthreads();
    int c0 = carry;
    int i = base + tid;
    int v = (i < nb) ? cnt[i] : 0;
    int x = v;
#pragma unroll
    for (int off = 1; off < 64; off <<= 1) {
      int t = __shfl_up(x, off);
      if (lane >= off) x += t;
    }
    if (lane == 63) wsum[wid] = x;
    __syncthreads();
    if (wid == 0) {
      int t = (lane < 16) ? wsum[lane] : 0;
#pragma unroll
      for (int off = 1; off < 16; off <<= 1) {
        int u = __shfl_up(t, off);
        if (lane >= off) t += u;
      }
      if (lane < 16) wsum[lane] = t;
    }
    __syncthreads();
    int wex = (wid == 0) ? 0 : wsum[wid - 1];
    int o = c0 + wex + (x - v);
    if (i < nb) boffs[i] = o;
    int total = wsum[15];
    __syncthreads();
    if (tid == 0) carry = c0 + total;
  }
  __syncthreads();
  if (tid == 0) { boffs[nb] = carry; offs[N] = E; }
}

// ---------- pass 2: per-bucket count/scan/scatter -> csr, offs, dinv ----------
__global__ __launch_bounds__(256) void k_bucket(const unsigned int* __restrict__ pair,
    const int* __restrict__ bcnt, const int* __restrict__ boffs,
    int* __restrict__ csr, int* __restrict__ offs, float* __restrict__ dinv,
    int N) {
  int b = blockIdx.x;
  int m = min(bcnt[b], CAP);
  __shared__ int cnt[128];
  __shared__ int noff[128];
  __shared__ int w0tot;
  if (threadIdx.x < 128) cnt[threadIdx.x] = 0;
  __syncthreads();
  const unsigned int* p = pair + (size_t)b * CAP;
  for (int i = threadIdx.x; i < m; i += 256)
    atomicAdd(&cnt[p[i] & 127u], 1);
  __syncthreads();
  int v = 0, x = 0;
  int lane = threadIdx.x & 63, w = threadIdx.x >> 6;
  if (threadIdx.x < 128) {
    v = cnt[threadIdx.x];
    x = v;
#pragma unroll
    for (int o = 1; o < 64; o <<= 1) {
      int t = __shfl_up(x, o);
      if (lane >= o) x += t;
    }
    if (threadIdx.x == 63) w0tot = x;
  }
  __syncthreads();
  int cbase = boffs[b];
  if (threadIdx.x < 128) {
    int ex = x - v + ((w == 1) ? w0tot : 0);
    int g = (b << BSHIFT) + threadIdx.x;
    if (g < N) {
      offs[g] = cbase + ex;
      dinv[g] = 1.0f / sqrtf((float)v + 1.0f);
    }
    noff[threadIdx.x] = ex;
    cnt[threadIdx.x] = 0;
  }
  __syncthreads();
  for (int i = threadIdx.x; i < m; i += 256) {
    unsigned pk = p[i];
    int d = pk & 127u;
    int pos = cbase + noff[d] + atomicAdd(&cnt[d], 1);
    csr[pos] = (int)(pk >> BSHIFT);
  }
}

// ---------- W prep: fp32 [k][col] -> fp16 transposed [col][k] ----------
__global__ __launch_bounds__(256) void k_wprep(const float* __restrict__ W,
    h16* __restrict__ WT) {
  int i = blockIdx.x * 256 + threadIdx.x;
  int k = i >> 7, c = i & 127;
  WT[c * FEAT + k] = (h16)W[(size_t)k * FEAT + c];
}

// ---------- gather core: 16 lanes/node, 16B (h16x8) per lane ----------
__device__ inline void acc8(f32x4& lo, f32x4& hi, h16x8 v) {
  lo[0] += (float)v[0]; lo[1] += (float)v[1]; lo[2] += (float)v[2]; lo[3] += (float)v[3];
  hi[0] += (float)v[4]; hi[1] += (float)v[5]; hi[2] += (float)v[6]; hi[3] += (float)v[7];
}

__device__ inline void gather_row8(const h16* __restrict__ XW,
    const int* __restrict__ offs, const int* __restrict__ csr,
    int node, int f0, f32x4& olo, f32x4& ohi) {
  f32x4 lo0 = {0,0,0,0}, hi0 = {0,0,0,0};
  f32x4 lo1 = {0,0,0,0}, hi1 = {0,0,0,0};
  f32x4 lo2 = {0,0,0,0}, hi2 = {0,0,0,0};
  f32x4 lo3 = {0,0,0,0}, hi3 = {0,0,0,0};
  h16x8 sv = *(const h16x8*)&XW[(size_t)node * FEAT + f0];   // self term
  acc8(lo0, hi0, sv);
  int s = offs[node], e = offs[node + 1];
  int i = s;
  for (; i + 8 <= e; i += 8) {
    int s0 = csr[i + 0], s1 = csr[i + 1], s2 = csr[i + 2], s3 = csr[i + 3];
    int s4 = csr[i + 4], s5 = csr[i + 5], s6 = csr[i + 6], s7 = csr[i + 7];
    h16x8 v0 = *(const h16x8*)&XW[(size_t)s0 * FEAT + f0];
    h16x8 v1 = *(const h16x8*)&XW[(size_t)s1 * FEAT + f0];
    h16x8 v2 = *(const h16x8*)&XW[(size_t)s2 * FEAT + f0];
    h16x8 v3 = *(const h16x8*)&XW[(size_t)s3 * FEAT + f0];
    h16x8 v4 = *(const h16x8*)&XW[(size_t)s4 * FEAT + f0];
    h16x8 v5 = *(const h16x8*)&XW[(size_t)s5 * FEAT + f0];
    h16x8 v6 = *(const h16x8*)&XW[(size_t)s6 * FEAT + f0];
    h16x8 v7 = *(const h16x8*)&XW[(size_t)s7 * FEAT + f0];
    acc8(lo0, hi0, v0); acc8(lo1, hi1, v1);
    acc8(lo2, hi2, v2); acc8(lo3, hi3, v3);
    acc8(lo0, hi0, v4); acc8(lo1, hi1, v5);
    acc8(lo2, hi2, v6); acc8(lo3, hi3, v7);
  }
  if (i + 4 <= e) {
    int s0 = csr[i + 0], s1 = csr[i + 1], s2 = csr[i + 2], s3 = csr[i + 3];
    h16x8 v0 = *(const h16x8*)&XW[(size_t)s0 * FEAT + f0];
    h16x8 v1 = *(const h16x8*)&XW[(size_t)s1 * FEAT + f0];
    h16x8 v2 = *(const h16x8*)&XW[(size_t)s2 * FEAT + f0];
    h16x8 v3 = *(const h16x8*)&XW[(size_t)s3 * FEAT + f0];
    acc8(lo0, hi0, v0); acc8(lo1, hi1, v1);
    acc8(lo2, hi2, v2); acc8(lo3, hi3, v3);
    i += 4;
  }
  for (; i < e; ++i) {
    int s0 = csr[i];
    h16x8 v0 = *(const h16x8*)&XW[(size_t)s0 * FEAT + f0];
    acc8(lo1, hi1, v0);
  }
  lo0[0]+=lo1[0]; lo0[1]+=lo1[1]; lo0[2]+=lo1[2]; lo0[3]+=lo1[3];
  hi0[0]+=hi1[0]; hi0[1]+=hi1[1]; hi0[2]+=hi1[2]; hi0[3]+=hi1[3];
  lo2[0]+=lo3[0]; lo2[1]+=lo3[1]; lo2[2]+=lo3[2]; lo2[3]+=lo3[3];
  hi2[0]+=hi3[0]; hi2[1]+=hi3[1]; hi2[2]+=hi3[2]; hi2[3]+=hi3[3];
  lo0[0]+=lo2[0]; lo0[1]+=lo2[1]; lo0[2]+=lo2[2]; lo0[3]+=lo2[3];
  hi0[0]+=hi2[0]; hi0[1]+=hi2[1]; hi0[2]+=hi2[2]; hi0[3]+=hi2[3];
  olo = lo0; ohi = hi0;
}

// -------- standalone aggregation: 16 nodes/block --------
__global__ __launch_bounds__(256) void k_agg(const h16* __restrict__ XW,
    const int* __restrict__ offs, const int* __restrict__ csr,
    const float* __restrict__ dinv, const float* __restrict__ bias,
    h16* __restrict__ out, int n) {
  int gid = threadIdx.x >> 4;
  int lane = threadIdx.x & 15;
  int node = blockIdx.x * 16 + gid;
  if (node >= n) return;
  int f0 = lane * 8;
  f32x4 lo, hi;
  gather_row8(XW, offs, csr, node, f0, lo, hi);
  float d = dinv[node];
  float4 b0 = *(const float4*)&bias[f0];
  float4 b1 = *(const float4*)&bias[f0 + 4];
  h16x8 o;
  o[0] = (h16)fmaxf(lo[0] * d + b0.x, 0.f);
  o[1] = (h16)fmaxf(lo[1] * d + b0.y, 0.f);
  o[2] = (h16)fmaxf(lo[2] * d + b0.z, 0.f);
  o[3] = (h16)fmaxf(lo[3] * d + b0.w, 0.f);
  o[4] = (h16)fmaxf(hi[0] * d + b1.x, 0.f);
  o[5] = (h16)fmaxf(hi[1] * d + b1.y, 0.f);
  o[6] = (h16)fmaxf(hi[2] * d + b1.z, 0.f);
  o[7] = (h16)fmaxf(hi[3] * d + b1.w, 0.f);
  *(h16x8*)&out[(size_t)node * FEAT + f0] = o;
}

// -------- fused aggregation + pvec --------
__global__ __launch_bounds__(256) void k_agg_pvec(const h16* __restrict__ XW,
    const int* __restrict__ offs, const int* __restrict__ csr,
    const float* __restrict__ dinv, const float* __restrict__ bias,
    const float* __restrict__ fcw, const float* __restrict__ fcb,
    float* __restrict__ p, int n) {
  int gid = threadIdx.x >> 4;
  int lane = threadIdx.x & 15;
  int node = blockIdx.x * 16 + gid;
  if (node >= n) return;
  int f0 = lane * 8;
  f32x4 lo, hi;
  gather_row8(XW, offs, csr, node, f0, lo, hi);
  float d = dinv[node];
  float4 b0 = *(const float4*)&bias[f0];
  float4 b1 = *(const float4*)&bias[f0 + 4];
  float4 w0 = *(const float4*)&fcw[f0];
  float4 w1 = *(const float4*)&fcw[f0 + 4];
  float acc = fmaxf(lo[0] * d + b0.x, 0.f) * w0.x
            + fmaxf(lo[1] * d + b0.y, 0.f) * w0.y
            + fmaxf(lo[2] * d + b0.z, 0.f) * w0.z
            + fmaxf(lo[3] * d + b0.w, 0.f) * w0.w
            + fmaxf(hi[0] * d + b1.x, 0.f) * w1.x
            + fmaxf(hi[1] * d + b1.y, 0.f) * w1.y
            + fmaxf(hi[2] * d + b1.z, 0.f) * w1.z
            + fmaxf(hi[3] * d + b1.w, 0.f) * w1.w;
#pragma unroll
  for (int off = 8; off > 0; off >>= 1) acc += __shfl_xor(acc, off, 16);
  if (lane == 0) p[node] = 1.0f / (1.0f + expf(-(acc + fcb[0])));
}

// -------- fused final aggregation + mean-pool partial (per graph,slice) --------
__global__ __launch_bounds__(256) void k_agg_pool(const h16* __restrict__ XW,
    const int* __restrict__ offs, const int* __restrict__ csr,
    const float* __restrict__ dinv, const float* __restrict__ bias,
    const int* __restrict__ batch, float* __restrict__ part, int n) {
  int g = blockIdx.x / PSL2;
  int s = blockIdx.x % PSL2;
  int lo_ = 0, hi_ = n;
  while (lo_ < hi_) { int m = (lo_ + hi_) >> 1; if (batch[m] < g) lo_ = m + 1; else hi_ = m; }
  int start = lo_;
  hi_ = n;
  while (lo_ < hi_) { int m = (lo_ + hi_) >> 1; if (batch[m] <= g) lo_ = m + 1; else hi_ = m; }
  int end = lo_;
  int len = end - start;
  int per = (len + PSL2 - 1) / PSL2;
  int r0 = start + s * per;
  int r1 = min(r0 + per, end);
  int gid = threadIdx.x >> 4;
  int lane = threadIdx.x & 15;
  int f0 = lane * 8;
  float4 b0 = *(const float4*)&bias[f0];
  float4 b1 = *(const float4*)&bias[f0 + 4];
  f32x4 plo = {0,0,0,0}, phi = {0,0,0,0};
  for (int node = r0 + gid; node < r1; node += 16) {
    f32x4 lo, hi;
    gather_row8(XW, offs, csr, node, f0, lo, hi);
    float d = dinv[node];
    plo[0] += fmaxf(lo[0] * d + b0.x, 0.f);
    plo[1] += fmaxf(lo[1] * d + b0.y, 0.f);
    plo[2] += fmaxf(lo[2] * d + b0.z, 0.f);
    plo[3] += fmaxf(lo[3] * d + b0.w, 0.f);
    phi[0] += fmaxf(hi[0] * d + b1.x, 0.f);
    phi[1] += fmaxf(hi[1] * d + b1.y, 0.f);
    phi[2] += fmaxf(hi[2] * d + b1.z, 0.f);
    phi[3] += fmaxf(hi[3] * d + b1.w, 0.f);
  }
  __shared__ float lds[16 * FEAT];
  *(f32x4*)&lds[gid * FEAT + f0] = plo;
  *(f32x4*)&lds[gid * FEAT + f0 + 4] = phi;
  __syncthreads();
  if (threadIdx.x < FEAT) {
    int f = threadIdx.x;
    float t = 0.f;
#pragma unroll
    for (int q = 0; q < 16; ++q) t += lds[q * FEAT + f];
    part[(size_t)blockIdx.x * FEAT + f] = t;
  }
}

// ---------- pool finalize: reduce slices, divide by count ----------
__global__ __launch_bounds__(128) void k_pool_fin(const float* __restrict__ part,
    const int* __restrict__ batch, float* __restrict__ out, int n) {
  int g = blockIdx.x;
  int lo = 0, hi = n;
  while (lo < hi) { int m = (lo + hi) >> 1; if (batch[m] < g) lo = m + 1; else hi = m; }
  int start = lo;
  hi = n;
  while (lo < hi) { int m = (lo + hi) >> 1; if (batch[m] <= g) lo = m + 1; else hi = m; }
  int len = lo - start;
  int f = threadIdx.x;
  float tot = 0.f;
#pragma unroll
  for (int s = 0; s < PSL2; ++s) tot += part[(size_t)(g * PSL2 + s) * FEAT + f];
  out[(size_t)g * FEAT + f] = tot / fmaxf((float)len, 1.0f);
}

// ---------------- MFMA GEMM ----------------
__device__ inline h16x8 load8(const float* p) {
  float4 a = *(const float4*)p, b = *(const float4*)(p + 4);
  h16x8 o;
  o[0] = (h16)a.x; o[1] = (h16)a.y; o[2] = (h16)a.z; o[3] = (h16)a.w;
  o[4] = (h16)b.x; o[5] = (h16)b.y; o[6] = (h16)b.z; o[7] = (h16)b.w;
  return o;
}
__device__ inline h16x8 load8(const h16* p) { return *(const h16x8*)p; }

template <typename TI>
__global__ __launch_bounds__(256) void k_gemm_mfma(const TI* __restrict__ X,
    const h16* __restrict__ WT, const float* __restrict__ s1, const float* __restrict__ s2,
    h16* __restrict__ Y, int n) {
  __shared__ __align__(16) h16 lA[128 * FEAT];
  __shared__ __align__(16) h16 lB[128 * FEAT];
  int tid = threadIdx.x;
  int row0 = blockIdx.x * 128;
#pragma unroll
  for (int i = 0; i < 8; ++i) {
    int c = tid + i * 256;
    int r = c >> 4, kc = c & 15;
    int grow = row0 + r;
    h16x8 v;
#pragma unroll
    for (int j = 0; j < 8; ++j) v[j] = (h16)0.f;
    if (grow < n) v = load8(&X[(size_t)grow * FEAT + kc * 8]);
    int byte = r * 256 + ((kc * 16) ^ ((r & 7) << 4));
    *(h16x8*)((char*)lA + byte) = v;
  }
#pragma unroll
  for (int i = 0; i < 8; ++i) {
    int c = tid + i * 256;
    int col = c >> 4, kc = c & 15;
    h16x8 v = *(const h16x8*)&WT[col * FEAT + kc * 8];
    int byte = col * 256 + ((kc * 16) ^ ((col & 7) << 4));
    *(h16x8*)((char*)lB + byte) = v;
  }
  __syncthreads();
  int w = tid >> 6, l = tid & 63;
  int lr = l & 15, lq = l >> 4;
  h16x8 af[2][4];
#pragma unroll
  for (int m = 0; m < 2; ++m)
#pragma unroll
    for (int s = 0; s < 4; ++s) {
      int r = w * 32 + m * 16 + lr;
      int k2 = (s * 32 + lq * 8) * 2;
      int byte = r * 256 + (k2 ^ ((r & 7) << 4));
      af[m][s] = *(const h16x8*)((const char*)lA + byte);
    }
  f32x4 acc[2][8];
#pragma unroll
  for (int m = 0; m < 2; ++m)
#pragma unroll
    for (int nn = 0; nn < 8; ++nn) acc[m][nn] = (f32x4){0.f, 0.f, 0.f, 0.f};
#pragma unroll
  for (int nn = 0; nn < 8; ++nn) {
#pragma unroll
    for (int s = 0; s < 4; ++s) {
      int col = nn * 16 + lr;
      int k2 = (s * 32 + lq * 8) * 2;
      int byte = col * 256 + (k2 ^ ((col & 7) << 4));
      h16x8 bf = *(const h16x8*)((const char*)lB + byte);
      acc[0][nn] = __builtin_amdgcn_mfma_f32_16x16x32_f16(af[0][s], bf, acc[0][nn], 0, 0, 0);
      acc[1][nn] = __builtin_amdgcn_mfma_f32_16x16x32_f16(af[1][s], bf, acc[1][nn], 0, 0, 0);
    }
  }
#pragma unroll
  for (int m = 0; m < 2; ++m) {
#pragma unroll
    for (int r = 0; r < 4; ++r) {
      int grow = row0 + w * 32 + m * 16 + lq * 4 + r;
      if (grow < n) {
        float sc = 1.0f;
        if (s1) sc = s1[grow];
        if (s2) sc *= s2[grow];
#pragma unroll
        for (int nn = 0; nn < 8; ++nn)
          Y[(size_t)grow * FEAT + nn * 16 + lr] = (h16)(acc[m][nn][r] * sc);
      }
    }
  }
}

extern "C" void kernel_launch(void* const* d_in, const int* in_sizes, int n_in,
                              void* d_out, int out_size, void* d_ws, size_t ws_size,
                              hipStream_t stream) {
  const float* x_H    = (const float*)d_in[0];
  const int*   ei_H   = (const int*)d_in[1];
  const float* x_G    = (const float*)d_in[2];
  const int*   ei_G   = (const int*)d_in[3];
  const int*   bat_H  = (const int*)d_in[4];
  const int*   bat_G  = (const int*)d_in[5];
  const float* sel_W1 = (const float*)d_in[6];
  const float* sel_b1 = (const float*)d_in[7];
  const float* sel_W2 = (const float*)d_in[8];
  const float* sel_b2 = (const float*)d_in[9];
  const float* sel_fcw = (const float*)d_in[10];
  const float* sel_fcb = (const float*)d_in[11];
  const float* emb_W1 = (const float*)d_in[12];
  const float* emb_b1 = (const float*)d_in[13];
  const float* emb_W2 = (const float*)d_in[14];
  const float* emb_b2 = (const float*)d_in[15];

  const int N = in_sizes[0] / FEAT;
  const int E = in_sizes[1] / 2;
  const int NG = 64;
  const int NB = (N + 127) >> BSHIFT;

  float* out = (float*)d_out;
  float* hF = out;
  float* hG = out + NG * FEAT;
  float* p  = out + 2 * NG * FEAT;

  char* ws = (char*)d_ws;
  size_t off = 0;
  auto alloc = [&](size_t bytes) -> void* {
    void* ptr = (void*)(ws + off);
    off += (bytes + 511) & ~(size_t)511;
    return ptr;
  };
  const size_t SZH = (size_t)N * FEAT * sizeof(h16);          // 25.6 MB
  const size_t SZP = (size_t)NB * CAP * sizeof(unsigned int); // 12.8 MB
  const size_t SZB = SZH > SZP ? SZH : SZP;
  h16* A       = (h16*)alloc(SZB);
  h16* B       = (h16*)alloc(SZB);
  h16* C       = (h16*)alloc(SZH);
  h16* x16H    = (h16*)alloc(SZH);
  float* dinvH = (float*)alloc((size_t)N * 4);
  float* dinvG = (float*)alloc((size_t)N * 4);
  int*  offsH  = (int*)alloc((size_t)(N + 1) * 4);
  int*  offsG  = (int*)alloc((size_t)(N + 1) * 4);
  int*  csrH   = (int*)alloc((size_t)E * 4);
  int*  csrG   = (int*)alloc((size_t)E * 4);
  int*  gcurH  = (int*)alloc((size_t)NB * 4);
  int*  gcurG  = (int*)alloc((size_t)NB * 4);
  int*  boffsH = (int*)alloc((size_t)(NB + 1) * 4);
  int*  boffsG = (int*)alloc((size_t)(NB + 1) * 4);
  float* part  = (float*)alloc((size_t)NG * PSL2 * FEAT * 4); // 1 MB
  h16* wtSel1  = (h16*)alloc((size_t)FEAT * FEAT * 2);
  h16* wtSel2  = (h16*)alloc((size_t)FEAT * FEAT * 2);
  h16* wtEmb1  = (h16*)alloc((size_t)FEAT * FEAT * 2);
  h16* wtEmb2  = (h16*)alloc((size_t)FEAT * FEAT * 2);
  (void)ws_size;

  unsigned int* pairH = (unsigned int*)A;
  unsigned int* pairG = (unsigned int*)B;

  const int gGemm = (N + 127) / 128;
  const int gAgg  = (N + 15) / 16;

  // ---- weight prep + x_H fp16 convert ----
  k_wprep<<<64, 256, 0, stream>>>(sel_W1, wtSel1);
  k_wprep<<<64, 256, 0, stream>>>(sel_W2, wtSel2);
  k_wprep<<<64, 256, 0, stream>>>(emb_W1, wtEmb1);
  k_wprep<<<64, 256, 0, stream>>>(emb_W2, wtEmb2);
  k_cvt<<<(N * FEAT / 8 + 255) / 256, 256, 0, stream>>>(x_H, x16H, N * FEAT / 8);

  // ---- build CSR for H and G ----
  hipMemsetAsync(gcurH, 0, (size_t)NB * 4, stream);
  hipMemsetAsync(gcurG, 0, (size_t)NB * 4, stream);
  k_part<<<256, 256, 0, stream>>>(ei_H, pairH, gcurH, E, NB);
  k_part<<<256, 256, 0, stream>>>(ei_G, pairG, gcurG, E, NB);
  k_bscan<<<1, 1024, 0, stream>>>(gcurH, boffsH, offsH, NB, N, E);
  k_bscan<<<1, 1024, 0, stream>>>(gcurG, boffsG, offsG, NB, N, E);
  k_bucket<<<NB, 256, 0, stream>>>(pairH, gcurH, boffsH, csrH, offsH, dinvH, N);
  k_bucket<<<NB, 256, 0, stream>>>(pairG, gcurG, boffsG, csrG, offsG, dinvG, N);

  // ---- selector: gemm1 -> agg -> gemm2 -> fused agg+pvec ----
  k_gemm_mfma<h16><<<gGemm, 256, 0, stream>>>(x16H, wtSel1, dinvH, nullptr, A, N);
  k_agg<<<gAgg, 256, 0, stream>>>(A, offsH, csrH, dinvH, sel_b1, B, N);
  k_gemm_mfma<h16><<<gGemm, 256, 0, stream>>>(B, wtSel2, dinvH, nullptr, C, N);
  k_agg_pvec<<<gAgg, 256, 0, stream>>>(C, offsH, csrH, dinvH, sel_b2, sel_fcw, sel_fcb, p, N);

  // ---- F branch: gemm1 -> agg -> gemm2 -> fused agg+pool ----
  k_gemm_mfma<h16><<<gGemm, 256, 0, stream>>>(x16H, wtEmb1, dinvH, p, A, N);
  k_agg<<<gAgg, 256, 0, stream>>>(A, offsH, csrH, dinvH, emb_b1, B, N);
  k_gemm_mfma<h16><<<gGemm, 256, 0, stream>>>(B, wtEmb2, dinvH, nullptr, C, N);
  k_agg_pool<<<NG * PSL2, 256, 0, stream>>>(C, offsH, csrH, dinvH, emb_b2, bat_H, part, N);
  k_pool_fin<<<NG, 128, 0, stream>>>(part, bat_H, hF, N);

  // ---- G branch ----
  k_gemm_mfma<float><<<gGemm, 256, 0, stream>>>(x_G, wtEmb1, dinvG, nullptr, A, N);
  k_agg<<<gAgg, 256, 0, stream>>>(A, offsG, csrG, dinvG, emb_b1, B, N);
  k_gemm_mfma<h16><<<gGemm, 256, 0, stream>>>(B, wtEmb2, dinvG, nullptr, C, N);
  k_agg_pool<<<NG * PSL2, 256, 0, stream>>>(C, offsG, csrG, dinvG, emb_b2, bat_G, part, N);
  k_pool_fin<<<NG, 128, 0, stream>>>(part, bat_G, hG, N);
}